// Round 1
// baseline (1111.440 us; speedup 1.0000x reference)
//
#include <hip/hip_runtime.h>

#define N_NODES 100000
#define N_EDGES 20000
#define DIM 64
#define HEADS 4
#define NNZ_ 500000
#define LNEPS 1e-5f

__device__ __forceinline__ float wsum64(float v){
#pragma unroll
  for (int off = 32; off; off >>= 1) v += __shfl_xor(v, off);
  return v;
}
// monotonic float->uint key for atomicMax on floats (handles negatives)
__device__ __forceinline__ unsigned fkey(float f){
  unsigned u = __float_as_uint(f);
  return (u & 0x80000000u) ? ~u : (u | 0x80000000u);
}
__device__ __forceinline__ float fdec(unsigned k){
  unsigned u = (k & 0x80000000u) ? (k & 0x7fffffffu) : ~k;
  return __uint_as_float(u);
}

// w_att_e[h][k] = sum_d att[0,h,D+d] * lin_w[h*D+d][k]   (folds eh away)
__global__ __launch_bounds__(256) void k_watt(const float* __restrict__ lin_w,
                                              const float* __restrict__ att,
                                              float* __restrict__ watte){
  int j = threadIdx.x;            // j = h*64 + k
  int h = j >> 6, k = j & 63;
  float s = 0.f;
#pragma unroll
  for (int d = 0; d < DIM; ++d)
    s += att[h*2*DIM + DIM + d] * lin_w[(h*DIM + d)*DIM + k];
  watte[j] = s;
}

// per-nnz scalar degree accumulations
__global__ __launch_bounds__(256) void k_deg(const int* __restrict__ row,
                                             const int* __restrict__ col,
                                             const float* __restrict__ val,
                                             float* __restrict__ colsum,
                                             float* __restrict__ bdeg,
                                             float* __restrict__ ddeg){
  int i = blockIdx.x*256 + threadIdx.x;
  if (i >= NNZ_) return;
  int c = col[i], r = row[i];
  atomicAdd(&colsum[c], val[i]);
  atomicAdd(&bdeg[c], 1.0f);
  atomicAdd(&ddeg[r], val[c]);   // reference: adj_val[adj_col[i]]
}

// omega_raw[e][d] += val[i] * x[row[i]][d]   (64 lanes per nnz)
__global__ __launch_bounds__(256) void k_omega(const int* __restrict__ row,
                                               const int* __restrict__ col,
                                               const float* __restrict__ val,
                                               const float* __restrict__ x,
                                               float* __restrict__ omega){
  size_t t = (size_t)blockIdx.x*256 + threadIdx.x;
  int i = (int)(t >> 6), d = (int)(t & 63);
  if (i >= NNZ_) return;
  atomicAdd(&omega[(size_t)col[i]*DIM + d], val[i] * x[(size_t)row[i]*DIM + d]);
}

// xh[n][j] = x[n]·lin_w[j]  (thread j holds lin_w row in 64 VGPRs, 128 nodes/block)
// also s_n[n][h] = sum_d xh[n][h][d]*att_x[h][d]  (wave h reduces its 64 lanes)
__global__ __launch_bounds__(256) void k_xh(const float* __restrict__ x,
                                            const float* __restrict__ lin_w,
                                            const float* __restrict__ att,
                                            float* __restrict__ xh,
                                            float* __restrict__ s_n){
  int j = threadIdx.x;
  int h = j >> 6, d = j & 63;
  float wreg[DIM];
  const float4* w4 = (const float4*)(lin_w + (size_t)j*DIM);
#pragma unroll
  for (int k = 0; k < DIM/4; ++k){
    float4 v = w4[k];
    wreg[4*k] = v.x; wreg[4*k+1] = v.y; wreg[4*k+2] = v.z; wreg[4*k+3] = v.w;
  }
  float attx = att[h*2*DIM + d];
  int n0 = blockIdx.x*128;
  int n1 = n0 + 128 < N_NODES ? n0 + 128 : N_NODES;
  for (int n = n0; n < n1; ++n){
    const float* xr = x + (size_t)n*DIM;
    float acc = 0.f;
#pragma unroll
    for (int k = 0; k < DIM; ++k) acc = fmaf(xr[k], wreg[k], acc);
    xh[(size_t)n*256 + j] = acc;
    float v = wsum64(acc * attx);
    if (d == 0) s_n[n*HEADS + h] = v;
  }
}

// s_e[e][h] = (omega_raw[e]·watte[h]) / colsum[e]
__global__ __launch_bounds__(256) void k_se(const float* __restrict__ omega,
                                            const float* __restrict__ colsum,
                                            const float* __restrict__ watte,
                                            float* __restrict__ s_e){
  int t = blockIdx.x*256 + threadIdx.x;
  if (t >= N_EDGES*HEADS) return;
  int e = t >> 2, h = t & 3;
  const float* om = omega + (size_t)e*DIM;
  const float* wv = watte + h*DIM;
  float acc = 0.f;
#pragma unroll
  for (int k = 0; k < DIM; ++k) acc = fmaf(om[k], wv[k], acc);
  s_e[t] = acc / colsum[e];
}

// pass A: raw alpha + leaky_relu, atomicMax per (edge,head)
__global__ __launch_bounds__(256) void k_alpha_a(const int* __restrict__ row,
                                                 const int* __restrict__ col,
                                                 const float* __restrict__ s_n,
                                                 const float* __restrict__ s_e,
                                                 float* __restrict__ araw,
                                                 unsigned* __restrict__ amaxu){
  size_t t = (size_t)blockIdx.x*256 + threadIdx.x;
  if (t >= (size_t)NNZ_*HEADS) return;
  int i = (int)(t >> 2), h = (int)(t & 3);
  int r = row[i], c = col[i];
  float a = s_n[r*HEADS + h] + s_e[c*HEADS + h];
  a = a > 0.f ? a : 0.2f*a;
  araw[t] = a;
  atomicMax(&amaxu[c*HEADS + h], fkey(a));
}

// pass B: ea = exp(a - amax), accumulate per-edge sum
__global__ __launch_bounds__(256) void k_alpha_b(const int* __restrict__ col,
                                                 float* __restrict__ araw,
                                                 const unsigned* __restrict__ amaxu,
                                                 float* __restrict__ asum){
  size_t t = (size_t)blockIdx.x*256 + threadIdx.x;
  if (t >= (size_t)NNZ_*HEADS) return;
  int i = (int)(t >> 2), h = (int)(t & 3);
  int c = col[i];
  float ea = expf(araw[t] - fdec(amaxu[c*HEADS + h]));
  araw[t] = ea;
  atomicAdd(&asum[c*HEADS + h], ea);
}

// pass C: normalize in place
__global__ __launch_bounds__(256) void k_alpha_c(const int* __restrict__ col,
                                                 float* __restrict__ araw,
                                                 const float* __restrict__ asum){
  size_t t = (size_t)blockIdx.x*256 + threadIdx.x;
  if (t >= (size_t)NNZ_*HEADS) return;
  int i = (int)(t >> 2), h = (int)(t & 3);
  araw[t] = araw[t] / asum[col[i]*HEADS + h];
}

// msg1: edge_out[c][h][d] += b_inv[c]*alpha[i][h]*xh[r][h][d]
__global__ __launch_bounds__(256) void k_msg1(const int* __restrict__ row,
                                              const int* __restrict__ col,
                                              const float* __restrict__ bdeg,
                                              const float* __restrict__ alpha,
                                              const float* __restrict__ xh,
                                              float* __restrict__ edge_out){
  size_t t = (size_t)blockIdx.x*256 + threadIdx.x;
  int i = (int)(t >> 6), d = (int)(t & 63);
  if (i >= NNZ_) return;
  int c = col[i], r = row[i];
  float binv = 1.0f / bdeg[c];
  const float* xr = xh + (size_t)r*256;
  float* eo = edge_out + (size_t)c*256;
#pragma unroll
  for (int h = 0; h < HEADS; ++h){
    float a = alpha[(size_t)i*HEADS + h] * binv;
    atomicAdd(&eo[h*DIM + d], a * xr[h*DIM + d]);
  }
}

// msg2 with mean-over-H folded: conv[r][d] += d_inv[r]*(1/H)*sum_h alpha[i][h]*eo[c][h][d]
__global__ __launch_bounds__(256) void k_msg2(const int* __restrict__ row,
                                              const int* __restrict__ col,
                                              const float* __restrict__ ddeg,
                                              const float* __restrict__ alpha,
                                              const float* __restrict__ edge_out,
                                              float* __restrict__ conv){
  size_t t = (size_t)blockIdx.x*256 + threadIdx.x;
  int i = (int)(t >> 6), d = (int)(t & 63);
  if (i >= NNZ_) return;
  int c = col[i], r = row[i];
  const float* eo = edge_out + (size_t)c*256;
  float s = 0.f;
#pragma unroll
  for (int h = 0; h < HEADS; ++h)
    s = fmaf(alpha[(size_t)i*HEADS + h], eo[h*DIM + d], s);
  float dinv = 1.0f / ddeg[r];
  atomicAdd(&conv[(size_t)r*DIM + d], dinv * 0.25f * s);
}

// fused epilogue: conv+bias+x -> LN1 -> FFN (no mid activation!) -> leaky -> +h -> LN2
__global__ __launch_bounds__(256) void k_final(const float* __restrict__ x,
                                               const float* __restrict__ conv,
                                               const float* __restrict__ bias,
                                               const float* __restrict__ g1,
                                               const float* __restrict__ b1g,
                                               const float* __restrict__ g2,
                                               const float* __restrict__ b2g,
                                               const float* __restrict__ w1,
                                               const float* __restrict__ b1,
                                               const float* __restrict__ w2,
                                               const float* __restrict__ b2,
                                               float* __restrict__ out){
  __shared__ float w1s[64*65];
  __shared__ float w2s[64*65];
  for (int idx = threadIdx.x; idx < 4096; idx += 256){
    int rr = idx >> 6, cc = idx & 63;
    w1s[rr*65 + cc] = w1[idx];
    w2s[rr*65 + cc] = w2[idx];
  }
  __syncthreads();
  int wave = threadIdx.x >> 6, lane = threadIdx.x & 63;
  float biasv = bias[lane];
  float g1v = g1[lane], b1gv = b1g[lane], g2v = g2[lane], b2gv = b2g[lane];
  float b1v = b1[lane], b2v = b2[lane];
  for (int n = blockIdx.x*4 + wave; n < N_NODES; n += gridDim.x*4){
    float t = x[(size_t)n*DIM + lane] + conv[(size_t)n*DIM + lane] + biasv;
    float mu = wsum64(t) * (1.f/64.f);
    float dv = t - mu;
    float var = wsum64(dv*dv) * (1.f/64.f);
    float hv = dv * rsqrtf(var + LNEPS) * g1v + b1gv;
    float acc = b1v;
#pragma unroll
    for (int k = 0; k < 64; ++k) acc = fmaf(__shfl(hv, k), w1s[lane*65 + k], acc);
    float acc2 = b2v;
#pragma unroll
    for (int k = 0; k < 64; ++k) acc2 = fmaf(__shfl(acc, k), w2s[lane*65 + k], acc2);
    float ffn = acc2 > 0.f ? acc2 : 0.01f*acc2;
    float t2 = hv + ffn;
    float mu2 = wsum64(t2) * (1.f/64.f);
    float dv2 = t2 - mu2;
    float var2 = wsum64(dv2*dv2) * (1.f/64.f);
    out[(size_t)n*DIM + lane] = dv2 * rsqrtf(var2 + LNEPS) * g2v + b2gv;
  }
}

extern "C" void kernel_launch(void* const* d_in, const int* in_sizes, int n_in,
                              void* d_out, int out_size, void* d_ws, size_t ws_size,
                              hipStream_t stream){
  const float* x     = (const float*)d_in[0];
  const int*   row   = (const int*)d_in[1];
  const int*   col   = (const int*)d_in[2];
  const float* val   = (const float*)d_in[3];
  const float* lin_w = (const float*)d_in[5];
  const float* att   = (const float*)d_in[6];
  const float* bias  = (const float*)d_in[7];
  const float* g1    = (const float*)d_in[8];
  const float* b1g   = (const float*)d_in[9];
  const float* g2    = (const float*)d_in[10];
  const float* b2g   = (const float*)d_in[11];
  const float* w1    = (const float*)d_in[12];
  const float* b1    = (const float*)d_in[13];
  const float* w2    = (const float*)d_in[14];
  const float* b2    = (const float*)d_in[15];
  float* out = (float*)d_out;
  float* ws  = (float*)d_ws;

  // ---- workspace layout (floats). Zeroed region first -> one memset. ----
  constexpr size_t off_colsum = 0;                                    // E
  constexpr size_t off_bdeg   = off_colsum + N_EDGES;                 // E
  constexpr size_t off_ddeg   = off_bdeg   + N_EDGES;                 // N
  constexpr size_t off_asum   = off_ddeg   + N_NODES;                 // E*H
  constexpr size_t off_amax   = off_asum   + (size_t)N_EDGES*HEADS;   // E*H (uint keys)
  constexpr size_t off_omega  = off_amax   + (size_t)N_EDGES*HEADS;   // E*D
  constexpr size_t off_eout   = off_omega  + (size_t)N_EDGES*DIM;     // E*H*D
  constexpr size_t off_conv   = off_eout   + (size_t)N_EDGES*HEADS*DIM; // N*D
  constexpr size_t ZEND       = off_conv   + (size_t)N_NODES*DIM;
  constexpr size_t off_watte  = ZEND;                                 // H*D
  constexpr size_t off_sn     = off_watte  + HEADS*DIM;               // N*H
  constexpr size_t off_se     = off_sn     + (size_t)N_NODES*HEADS;   // E*H
  constexpr size_t off_araw   = off_se     + (size_t)N_EDGES*HEADS;   // NNZ*H
  constexpr size_t off_xh     = off_araw   + (size_t)NNZ_*HEADS;      // N*H*D

  float*    colsum = ws + off_colsum;
  float*    bdeg   = ws + off_bdeg;
  float*    ddeg   = ws + off_ddeg;
  float*    asum   = ws + off_asum;
  unsigned* amaxu  = (unsigned*)(ws + off_amax);
  float*    omega  = ws + off_omega;
  float*    eout   = ws + off_eout;
  float*    conv   = ws + off_conv;
  float*    watte  = ws + off_watte;
  float*    sn     = ws + off_sn;
  float*    se     = ws + off_se;
  float*    araw   = ws + off_araw;
  float*    xh     = ws + off_xh;

  hipMemsetAsync(ws, 0, ZEND*sizeof(float), stream);   // zero all accumulators

  k_watt<<<1, 256, 0, stream>>>(lin_w, att, watte);
  k_deg<<<(NNZ_ + 255)/256, 256, 0, stream>>>(row, col, val, colsum, bdeg, ddeg);
  k_omega<<<(int)(((size_t)NNZ_*64 + 255)/256), 256, 0, stream>>>(row, col, val, x, omega);
  k_xh<<<(N_NODES + 127)/128, 256, 0, stream>>>(x, lin_w, att, xh, sn);
  k_se<<<(N_EDGES*HEADS + 255)/256, 256, 0, stream>>>(omega, colsum, watte, se);

  int agrid = (int)(((size_t)NNZ_*HEADS + 255)/256);
  k_alpha_a<<<agrid, 256, 0, stream>>>(row, col, sn, se, araw, amaxu);
  k_alpha_b<<<agrid, 256, 0, stream>>>(col, araw, amaxu, asum);
  k_alpha_c<<<agrid, 256, 0, stream>>>(col, araw, asum);

  int mgrid = (int)(((size_t)NNZ_*64 + 255)/256);
  k_msg1<<<mgrid, 256, 0, stream>>>(row, col, bdeg, araw, xh, eout);
  k_msg2<<<mgrid, 256, 0, stream>>>(row, col, ddeg, araw, eout, conv);

  k_final<<<1024, 256, 0, stream>>>(x, conv, bias, g1, b1g, g2, b2g, w1, b1, w2, b2, out);
}

// Round 2
// 1070.517 us; speedup vs baseline: 1.0382x; 1.0382x over previous
//
#include <hip/hip_runtime.h>

#define N_NODES 100000
#define N_EDGES 20000
#define DIM 64
#define HEADS 4
#define NNZ_ 500000
#define LNEPS 1e-5f

__device__ __forceinline__ float wsum64(float v){
#pragma unroll
  for (int off = 32; off; off >>= 1) v += __shfl_xor(v, off);
  return v;
}
__device__ __forceinline__ float wmax64(float v){
#pragma unroll
  for (int off = 32; off; off >>= 1) v = fmaxf(v, __shfl_xor(v, off));
  return v;
}
__device__ __forceinline__ float lrelu2(float a){ return a > 0.f ? a : 0.2f*a; }

// ---- phase 1: histogram + degree sums ----
__global__ __launch_bounds__(256) void k_hist(const int* __restrict__ row,
                                              const int* __restrict__ col,
                                              const float* __restrict__ val,
                                              int* __restrict__ ecnt, int* __restrict__ ncnt,
                                              float* __restrict__ colsum, float* __restrict__ ddeg){
  int i = blockIdx.x*256 + threadIdx.x;
  if (i >= NNZ_) return;
  int c = col[i], r = row[i];
  atomicAdd(&ecnt[c], 1);
  atomicAdd(&ncnt[r], 1);
  atomicAdd(&colsum[c], val[i]);
  atomicAdd(&ddeg[r], val[c]);   // reference: adj_val[adj_col[i]]
}

// ---- single-block tiled exclusive scan (counts -> ptr[n+1]) ----
__global__ __launch_bounds__(1024) void k_scan(const int* __restrict__ cnt,
                                               int* __restrict__ ptr, int n){
  __shared__ int wsums[16];
  __shared__ int carryS;
  if (threadIdx.x == 0) carryS = 0;
  __syncthreads();
  int lane = threadIdx.x & 63, wid = threadIdx.x >> 6;
  for (int base = 0; base < n; base += 1024){
    int idx = base + threadIdx.x;
    int v = (idx < n) ? cnt[idx] : 0;
    int s = v;
#pragma unroll
    for (int off = 1; off < 64; off <<= 1){
      int t = __shfl_up(s, off);
      if (lane >= off) s += t;
    }
    if (lane == 63) wsums[wid] = s;
    __syncthreads();
    if (wid == 0 && lane < 16){
      int ws = wsums[lane];
      int t = ws;
#pragma unroll
      for (int off = 1; off < 16; off <<= 1){
        int u = __shfl_up(t, off);
        if (lane >= off) t += u;
      }
      wsums[lane] = t - ws;   // exclusive prefix of wave sums
    }
    __syncthreads();
    int carry = carryS;
    if (idx < n) ptr[idx] = carry + wsums[wid] + s - v;
    __syncthreads();
    if (threadIdx.x == 1023) carryS = carry + wsums[15] + s;
    __syncthreads();
  }
  if (threadIdx.x == 0) ptr[n] = carryS;
}

// ---- scatter nnz indices into CSR slots ----
__global__ __launch_bounds__(256) void k_scatter(const int* __restrict__ row,
                                                 const int* __restrict__ col,
                                                 const int* __restrict__ colptr,
                                                 const int* __restrict__ rowptr,
                                                 int* __restrict__ ecur, int* __restrict__ ncur,
                                                 int* __restrict__ permC, int* __restrict__ permR){
  int i = blockIdx.x*256 + threadIdx.x;
  if (i >= NNZ_) return;
  int c = col[i], r = row[i];
  int p = atomicAdd(&ecur[c], 1);
  permC[colptr[c] + p] = i;
  int q = atomicAdd(&ncur[r], 1);
  permR[rowptr[r] + q] = i;
}

// ---- folded attention vectors: wattx[h][k]=att_x[h]·lin_w_h col k ; watte likewise ----
__global__ __launch_bounds__(256) void k_watt(const float* __restrict__ lin_w,
                                              const float* __restrict__ att,
                                              float* __restrict__ wattx,
                                              float* __restrict__ watte){
  int j = threadIdx.x;           // j = h*64 + k
  int h = j >> 6, k = j & 63;
  float sx = 0.f, se = 0.f;
#pragma unroll
  for (int d = 0; d < DIM; ++d){
    float w = lin_w[(h*DIM + d)*DIM + k];
    sx = fmaf(att[h*2*DIM + d],        w, sx);
    se = fmaf(att[h*2*DIM + DIM + d],  w, se);
  }
  wattx[j] = sx;
  watte[j] = se;
}

// ---- per-node projections: sn[n][h]=x[n]·wattx_h (=s_n), pe[n][h]=x[n]·watte_h ----
__global__ __launch_bounds__(1024) void k_pre(const float* __restrict__ x,
                                              const float* __restrict__ wattx,
                                              const float* __restrict__ watte,
                                              float4* __restrict__ sn4,
                                              float4* __restrict__ pe4){
  int lane = threadIdx.x & 63, wid = threadIdx.x >> 6;
  int n = blockIdx.x*16 + wid;
  if (n >= N_NODES) return;
  float wx0 = wattx[lane], wx1 = wattx[64+lane], wx2 = wattx[128+lane], wx3 = wattx[192+lane];
  float we0 = watte[lane], we1 = watte[64+lane], we2 = watte[128+lane], we3 = watte[192+lane];
  float xv = x[(size_t)n*DIM + lane];
  float s0 = wsum64(xv*wx0), s1 = wsum64(xv*wx1), s2 = wsum64(xv*wx2), s3 = wsum64(xv*wx3);
  float p0 = wsum64(xv*we0), p1 = wsum64(xv*we1), p2 = wsum64(xv*we2), p3 = wsum64(xv*we3);
  if (lane == 0){
    sn4[n] = make_float4(s0,s1,s2,s3);
    pe4[n] = make_float4(p0,p1,p2,p3);
  }
}

// ---- per-edge softmax -> normalized alpha[nnz][4] ----
__global__ __launch_bounds__(1024) void k_soft(const int* __restrict__ permC,
                                               const int* __restrict__ colptr,
                                               const int* __restrict__ row,
                                               const float* __restrict__ val,
                                               const float4* __restrict__ sn4,
                                               const float4* __restrict__ pe4,
                                               const float* __restrict__ colsum,
                                               float4* __restrict__ alpha4){
  int lane = threadIdx.x & 63, wid = threadIdx.x >> 6;
  int e = blockIdx.x*16 + wid;
  if (e >= N_EDGES) return;
  int s = colptr[e], cnt = colptr[e+1] - s;
  if (cnt == 0) return;
  float rcs = 1.0f / colsum[e];

  if (cnt <= 64){
    int i = 0, r = 0; float v = 0.f;
    float4 p = make_float4(0,0,0,0), snv = make_float4(0,0,0,0);
    bool act = lane < cnt;
    if (act){ i = permC[s+lane]; r = row[i]; v = val[i]; p = pe4[r]; snv = sn4[r]; }
    float se0 = wsum64(v*p.x)*rcs, se1 = wsum64(v*p.y)*rcs,
          se2 = wsum64(v*p.z)*rcs, se3 = wsum64(v*p.w)*rcs;
    float t0 = act ? lrelu2(snv.x+se0) : -1e30f;
    float t1 = act ? lrelu2(snv.y+se1) : -1e30f;
    float t2 = act ? lrelu2(snv.z+se2) : -1e30f;
    float t3 = act ? lrelu2(snv.w+se3) : -1e30f;
    float m0 = wmax64(t0), m1 = wmax64(t1), m2 = wmax64(t2), m3 = wmax64(t3);
    float e0 = act ? __expf(t0-m0) : 0.f;
    float e1 = act ? __expf(t1-m1) : 0.f;
    float e2 = act ? __expf(t2-m2) : 0.f;
    float e3 = act ? __expf(t3-m3) : 0.f;
    float q0 = wsum64(e0), q1 = wsum64(e1), q2 = wsum64(e2), q3 = wsum64(e3);
    if (act) alpha4[i] = make_float4(e0/q0, e1/q1, e2/q2, e3/q3);
    return;
  }
  // rare slow path (cnt > 64): chunked multi-pass with recompute
  float a0=0,a1=0,a2=0,a3=0;
  for (int base = 0; base < cnt; base += 64){
    int j = base + lane;
    if (j < cnt){
      int i = permC[s+j]; int r = row[i]; float v = val[i];
      float4 p = pe4[r];
      a0 = fmaf(v,p.x,a0); a1 = fmaf(v,p.y,a1); a2 = fmaf(v,p.z,a2); a3 = fmaf(v,p.w,a3);
    }
  }
  float se0 = wsum64(a0)*rcs, se1 = wsum64(a1)*rcs, se2 = wsum64(a2)*rcs, se3 = wsum64(a3)*rcs;
  float m0=-1e30f,m1=-1e30f,m2=-1e30f,m3=-1e30f;
  for (int base = 0; base < cnt; base += 64){
    int j = base + lane;
    if (j < cnt){
      int i = permC[s+j]; float4 snv = sn4[row[i]];
      m0 = fmaxf(m0, lrelu2(snv.x+se0)); m1 = fmaxf(m1, lrelu2(snv.y+se1));
      m2 = fmaxf(m2, lrelu2(snv.z+se2)); m3 = fmaxf(m3, lrelu2(snv.w+se3));
    }
  }
  m0 = wmax64(m0); m1 = wmax64(m1); m2 = wmax64(m2); m3 = wmax64(m3);
  float q0=0,q1=0,q2=0,q3=0;
  for (int base = 0; base < cnt; base += 64){
    int j = base + lane;
    if (j < cnt){
      int i = permC[s+j]; float4 snv = sn4[row[i]];
      float e0 = __expf(lrelu2(snv.x+se0)-m0), e1 = __expf(lrelu2(snv.y+se1)-m1);
      float e2 = __expf(lrelu2(snv.z+se2)-m2), e3 = __expf(lrelu2(snv.w+se3)-m3);
      q0+=e0; q1+=e1; q2+=e2; q3+=e3;
      alpha4[i] = make_float4(e0,e1,e2,e3);
    }
  }
  q0 = wsum64(q0); q1 = wsum64(q1); q2 = wsum64(q2); q3 = wsum64(q3);
  float r0 = 1.f/q0, r1 = 1.f/q1, r2 = 1.f/q2, r3 = 1.f/q3;
  for (int base = 0; base < cnt; base += 64){
    int j = base + lane;
    if (j < cnt){
      int i = permC[s+j]; float4 a = alpha4[i];
      alpha4[i] = make_float4(a.x*r0, a.y*r1, a.z*r2, a.w*r3);
    }
  }
}

// ---- msg1 in x-space + per-edge lin_w transform -> eo[e][h][d] (h-space) ----
__global__ __launch_bounds__(1024) void k_msg1t(const int* __restrict__ permC,
                                                const int* __restrict__ colptr,
                                                const int* __restrict__ row,
                                                const float4* __restrict__ alpha4,
                                                const float* __restrict__ x,
                                                const float* __restrict__ lin_w,
                                                float* __restrict__ eo){
  __shared__ float lwT[4*64*64];   // [h][k][d] = lin_w[(h*64+d)*64+k]  (64 KB)
  for (int idx = threadIdx.x; idx < 4*64*64; idx += 1024){
    int k = idx & 63, hd = idx >> 6;
    int d = hd & 63, h = hd >> 6;
    lwT[((h*64 + k)*64) + d] = lin_w[idx];
  }
  __syncthreads();
  int lane = threadIdx.x & 63, wid = threadIdx.x >> 6;
  for (int e = blockIdx.x*16 + wid; e < N_EDGES; e += gridDim.x*16){
    int s = colptr[e], cnt = colptr[e+1] - s;
    float acc0=0,acc1=0,acc2=0,acc3=0;
#pragma unroll 2
    for (int j = 0; j < cnt; ++j){
      int i = permC[s+j];
      int r = row[i];
      float4 al = alpha4[i];
      float xv = x[(size_t)r*DIM + lane];
      acc0 = fmaf(al.x, xv, acc0); acc1 = fmaf(al.y, xv, acc1);
      acc2 = fmaf(al.z, xv, acc2); acc3 = fmaf(al.w, xv, acc3);
    }
    float binv = cnt > 0 ? 1.0f/(float)cnt : 0.f;
    acc0 *= binv; acc1 *= binv; acc2 *= binv; acc3 *= binv;
    float o0=0,o1=0,o2=0,o3=0;
#pragma unroll
    for (int k = 0; k < 64; ++k){
      o0 = fmaf(__shfl(acc0,k), lwT[(0*64+k)*64 + lane], o0);
      o1 = fmaf(__shfl(acc1,k), lwT[(1*64+k)*64 + lane], o1);
      o2 = fmaf(__shfl(acc2,k), lwT[(2*64+k)*64 + lane], o2);
      o3 = fmaf(__shfl(acc3,k), lwT[(3*64+k)*64 + lane], o3);
    }
    size_t b = (size_t)e*256;
    eo[b      + lane] = o0;
    eo[b + 64 + lane] = o1;
    eo[b +128 + lane] = o2;
    eo[b +192 + lane] = o3;
  }
}

// ---- msg2: per-node gather of eo, mean over heads -> conv ----
__global__ __launch_bounds__(1024) void k_msg2(const int* __restrict__ permR,
                                               const int* __restrict__ rowptr,
                                               const int* __restrict__ col,
                                               const float4* __restrict__ alpha4,
                                               const float* __restrict__ eo,
                                               const float* __restrict__ ddeg,
                                               float* __restrict__ conv){
  int lane = threadIdx.x & 63, wid = threadIdx.x >> 6;
  int n = blockIdx.x*16 + wid;
  if (n >= N_NODES) return;
  int s = rowptr[n], cnt = rowptr[n+1] - s;
  float a0=0,a1=0,a2=0,a3=0;
#pragma unroll 2
  for (int j = 0; j < cnt; ++j){
    int i = permR[s+j];
    int c = col[i];
    float4 al = alpha4[i];
    size_t b = (size_t)c*256;
    a0 = fmaf(al.x, eo[b      + lane], a0);
    a1 = fmaf(al.y, eo[b + 64 + lane], a1);
    a2 = fmaf(al.z, eo[b +128 + lane], a2);
    a3 = fmaf(al.w, eo[b +192 + lane], a3);
  }
  float dd = ddeg[n];
  float dinv = dd > 0.f ? 0.25f/dd : 0.f;
  conv[(size_t)n*DIM + lane] = (a0+a1+a2+a3)*dinv;
}

// ---- fused epilogue: x+conv+bias -> LN1 -> FFN -> +h -> LN2 -> out ----
__global__ __launch_bounds__(256) void k_final(const float* __restrict__ x,
                                               const float* __restrict__ conv,
                                               const float* __restrict__ bias,
                                               const float* __restrict__ g1,
                                               const float* __restrict__ b1g,
                                               const float* __restrict__ g2,
                                               const float* __restrict__ b2g,
                                               const float* __restrict__ w1,
                                               const float* __restrict__ b1,
                                               const float* __restrict__ w2,
                                               const float* __restrict__ b2,
                                               float* __restrict__ out){
  __shared__ float w1s[64*65];
  __shared__ float w2s[64*65];
  for (int idx = threadIdx.x; idx < 4096; idx += 256){
    int rr = idx >> 6, cc = idx & 63;
    w1s[rr*65 + cc] = w1[idx];
    w2s[rr*65 + cc] = w2[idx];
  }
  __syncthreads();
  int wave = threadIdx.x >> 6, lane = threadIdx.x & 63;
  float biasv = bias[lane];
  float g1v = g1[lane], b1gv = b1g[lane], g2v = g2[lane], b2gv = b2g[lane];
  float b1v = b1[lane], b2v = b2[lane];
  for (int n = blockIdx.x*4 + wave; n < N_NODES; n += gridDim.x*4){
    float t = x[(size_t)n*DIM + lane] + conv[(size_t)n*DIM + lane] + biasv;
    float mu = wsum64(t) * (1.f/64.f);
    float dv = t - mu;
    float var = wsum64(dv*dv) * (1.f/64.f);
    float hv = dv * rsqrtf(var + LNEPS) * g1v + b1gv;
    float acc = b1v;
#pragma unroll
    for (int k = 0; k < 64; ++k) acc = fmaf(__shfl(hv, k), w1s[lane*65 + k], acc);
    float acc2 = b2v;
#pragma unroll
    for (int k = 0; k < 64; ++k) acc2 = fmaf(__shfl(acc, k), w2s[lane*65 + k], acc2);
    float ffn = acc2 > 0.f ? acc2 : 0.01f*acc2;
    float t2 = hv + ffn;
    float mu2 = wsum64(t2) * (1.f/64.f);
    float dv2 = t2 - mu2;
    float var2 = wsum64(dv2*dv2) * (1.f/64.f);
    out[(size_t)n*DIM + lane] = dv2 * rsqrtf(var2 + LNEPS) * g2v + b2gv;
  }
}

extern "C" void kernel_launch(void* const* d_in, const int* in_sizes, int n_in,
                              void* d_out, int out_size, void* d_ws, size_t ws_size,
                              hipStream_t stream){
  const float* x     = (const float*)d_in[0];
  const int*   row   = (const int*)d_in[1];
  const int*   col   = (const int*)d_in[2];
  const float* val   = (const float*)d_in[3];
  const float* lin_w = (const float*)d_in[5];
  const float* att   = (const float*)d_in[6];
  const float* bias  = (const float*)d_in[7];
  const float* g1    = (const float*)d_in[8];
  const float* b1g   = (const float*)d_in[9];
  const float* g2    = (const float*)d_in[10];
  const float* b2g   = (const float*)d_in[11];
  const float* w1    = (const float*)d_in[12];
  const float* b1    = (const float*)d_in[13];
  const float* w2    = (const float*)d_in[14];
  const float* b2    = (const float*)d_in[15];
  float* out = (float*)d_out;
  float* ws  = (float*)d_ws;

  constexpr size_t E = N_EDGES, Nn = N_NODES;
  // zeroed region (one memset): int counters + float degree sums
  constexpr size_t o_ecnt   = 0;                  // E ints
  constexpr size_t o_ncnt   = o_ecnt + E;         // N ints
  constexpr size_t o_ecur   = o_ncnt + Nn;        // E ints
  constexpr size_t o_ncur   = o_ecur + E;         // N ints
  constexpr size_t o_colsum = o_ncur + Nn;        // E floats
  constexpr size_t o_ddeg   = o_colsum + E;       // N floats
  constexpr size_t ZEND     = o_ddeg + Nn;
  constexpr size_t o_colptr = ZEND;               // E+4 ints
  constexpr size_t o_rowptr = o_colptr + E + 4;   // N+4 ints
  constexpr size_t o_permC  = o_rowptr + Nn + 4;  // NNZ ints
  constexpr size_t o_permR  = o_permC + NNZ_;     // NNZ ints
  constexpr size_t o_wattx  = o_permR + NNZ_;     // 256 f
  constexpr size_t o_watte  = o_wattx + 256;      // 256 f
  constexpr size_t o_sn     = o_watte + 256;      // 4N f (float4)
  constexpr size_t o_pe     = o_sn + 4*Nn;        // 4N f
  constexpr size_t o_alpha  = o_pe + 4*Nn;        // 4*NNZ f
  constexpr size_t o_eo     = o_alpha + 4*(size_t)NNZ_; // 256*E f
  constexpr size_t o_conv   = o_eo + 256*E;       // 64*N f

  int*    ecnt   = (int*)(ws + o_ecnt);
  int*    ncnt   = (int*)(ws + o_ncnt);
  int*    ecur   = (int*)(ws + o_ecur);
  int*    ncur   = (int*)(ws + o_ncur);
  float*  colsum = ws + o_colsum;
  float*  ddeg   = ws + o_ddeg;
  int*    colptr = (int*)(ws + o_colptr);
  int*    rowptr = (int*)(ws + o_rowptr);
  int*    permC  = (int*)(ws + o_permC);
  int*    permR  = (int*)(ws + o_permR);
  float*  wattx  = ws + o_wattx;
  float*  watte  = ws + o_watte;
  float4* sn4    = (float4*)(ws + o_sn);
  float4* pe4    = (float4*)(ws + o_pe);
  float4* alpha4 = (float4*)(ws + o_alpha);
  float*  eo     = ws + o_eo;
  float*  conv   = ws + o_conv;

  hipMemsetAsync(ws, 0, ZEND*sizeof(float), stream);

  k_hist<<<(NNZ_+255)/256, 256, 0, stream>>>(row, col, val, ecnt, ncnt, colsum, ddeg);
  k_scan<<<1, 1024, 0, stream>>>(ecnt, colptr, (int)E);
  k_scan<<<1, 1024, 0, stream>>>(ncnt, rowptr, (int)Nn);
  k_scatter<<<(NNZ_+255)/256, 256, 0, stream>>>(row, col, colptr, rowptr, ecur, ncur, permC, permR);

  k_watt<<<1, 256, 0, stream>>>(lin_w, att, wattx, watte);
  k_pre<<<(int)((Nn+15)/16), 1024, 0, stream>>>(x, wattx, watte, sn4, pe4);
  k_soft<<<(int)((E+15)/16), 1024, 0, stream>>>(permC, colptr, row, val, sn4, pe4, colsum, alpha4);
  k_msg1t<<<512, 1024, 0, stream>>>(permC, colptr, row, alpha4, x, lin_w, eo);
  k_msg2<<<(int)((Nn+15)/16), 1024, 0, stream>>>(permR, rowptr, col, alpha4, eo, ddeg, conv);
  k_final<<<1024, 256, 0, stream>>>(x, conv, bias, g1, b1g, g2, b2g, w1, b1, w2, b2, out);
}

// Round 3
// 615.696 us; speedup vs baseline: 1.8052x; 1.7387x over previous
//
#include <hip/hip_runtime.h>

#define N_NODES 100000
#define N_EDGES 20000
#define DIM 64
#define HEADS 4
#define NNZ_ 500000
#define LNEPS 1e-5f

__device__ __forceinline__ float wsum64(float v){
#pragma unroll
  for (int off = 32; off; off >>= 1) v += __shfl_xor(v, off);
  return v;
}
__device__ __forceinline__ float wmax64(float v){
#pragma unroll
  for (int off = 32; off; off >>= 1) v = fmaxf(v, __shfl_xor(v, off));
  return v;
}
__device__ __forceinline__ float lrelu2(float a){ return a > 0.f ? a : 0.2f*a; }

// ---- histogram + degree sums ----
__global__ __launch_bounds__(256) void k_hist(const int* __restrict__ row,
                                              const int* __restrict__ col,
                                              const float* __restrict__ val,
                                              int* __restrict__ ecnt, int* __restrict__ ncnt,
                                              float* __restrict__ colsum, float* __restrict__ ddeg){
  int i = blockIdx.x*256 + threadIdx.x;
  if (i >= NNZ_) return;
  int c = col[i], r = row[i];
  atomicAdd(&ecnt[c], 1);
  atomicAdd(&ncnt[r], 1);
  atomicAdd(&colsum[c], val[i]);
  atomicAdd(&ddeg[r], val[c]);   // reference: adj_val[adj_col[i]]
}

// ---- hierarchical scan: A per-block, B block-sums, C add offsets ----
__global__ __launch_bounds__(1024) void k_scanA(const int* __restrict__ cnt,
                                                int* __restrict__ ptr,
                                                int* __restrict__ bsum, int n){
  __shared__ int wsums[16];
  int idx = blockIdx.x*1024 + threadIdx.x;
  int lane = threadIdx.x & 63, wid = threadIdx.x >> 6;
  int v = (idx < n) ? cnt[idx] : 0;
  int s = v;
#pragma unroll
  for (int off = 1; off < 64; off <<= 1){
    int t = __shfl_up(s, off);
    if (lane >= off) s += t;
  }
  if (lane == 63) wsums[wid] = s;
  __syncthreads();
  if (wid == 0 && lane < 16){
    int ws = wsums[lane];
    int t = ws;
#pragma unroll
    for (int off = 1; off < 16; off <<= 1){
      int u = __shfl_up(t, off);
      if (lane >= off) t += u;
    }
    wsums[lane] = t - ws;   // exclusive wave prefix
  }
  __syncthreads();
  if (idx < n) ptr[idx] = wsums[wid] + s - v;
  if (threadIdx.x == 1023) bsum[blockIdx.x] = wsums[15] + s;
}

__global__ __launch_bounds__(256) void k_scanB(int* __restrict__ bsum, int nb,
                                               int* __restrict__ ptr, int n){
  __shared__ int sh[256];
  int t = threadIdx.x;
  int v = (t < nb) ? bsum[t] : 0;
  sh[t] = v;
  __syncthreads();
  for (int off = 1; off < 256; off <<= 1){
    int u = (t >= off) ? sh[t-off] : 0;
    __syncthreads();
    sh[t] += u;
    __syncthreads();
  }
  if (t < nb) bsum[t] = sh[t] - v;    // exclusive
  if (t == nb-1) ptr[n] = sh[t];      // total
}

__global__ __launch_bounds__(1024) void k_scanC(int* __restrict__ ptr,
                                                const int* __restrict__ bsum, int n){
  int idx = blockIdx.x*1024 + threadIdx.x;
  if (idx < n) ptr[idx] += bsum[blockIdx.x];
}

// ---- scatter: build permuted metadata copies (sequential reads downstream) ----
__global__ __launch_bounds__(256) void k_scatter(const int* __restrict__ row,
                                                 const int* __restrict__ col,
                                                 const float* __restrict__ val,
                                                 const int* __restrict__ colptr,
                                                 const int* __restrict__ rowptr,
                                                 int* __restrict__ ecur, int* __restrict__ ncur,
                                                 int* __restrict__ rowC, float* __restrict__ valC,
                                                 int* __restrict__ rposC, int* __restrict__ colR){
  int i = blockIdx.x*256 + threadIdx.x;
  if (i >= NNZ_) return;
  int c = col[i], r = row[i];
  int p = atomicAdd(&ecur[c], 1);
  int q = atomicAdd(&ncur[r], 1);
  int cpos = colptr[c] + p;
  int rpos = rowptr[r] + q;
  rowC[cpos] = r;
  valC[cpos] = val[i];
  rposC[cpos] = rpos;
  colR[rpos] = c;
}

// ---- folded attention vectors ----
__global__ __launch_bounds__(256) void k_watt(const float* __restrict__ lin_w,
                                              const float* __restrict__ att,
                                              float* __restrict__ wattx,
                                              float* __restrict__ watte){
  int j = threadIdx.x;           // j = h*64 + k
  int h = j >> 6;
  float sx = 0.f, se = 0.f;
#pragma unroll
  for (int d = 0; d < DIM; ++d){
    float w = lin_w[(h*DIM + d)*DIM + (j & 63)];
    sx = fmaf(att[h*2*DIM + d],       w, sx);
    se = fmaf(att[h*2*DIM + DIM + d], w, se);
  }
  wattx[j] = sx;
  watte[j] = se;
}

// ---- per-node projections, packed: snpe[2n]=s_n, snpe[2n+1]=pe ----
__global__ __launch_bounds__(256) void k_pre(const float* __restrict__ x,
                                             const float* __restrict__ wattx,
                                             const float* __restrict__ watte,
                                             float4* __restrict__ snpe){
  int lane = threadIdx.x & 63, wid = threadIdx.x >> 6;
  int n = blockIdx.x*4 + wid;
  if (n >= N_NODES) return;
  float xv = x[(size_t)n*DIM + lane];
  float s0 = wsum64(xv*wattx[lane]);
  float s1 = wsum64(xv*wattx[64+lane]);
  float s2 = wsum64(xv*wattx[128+lane]);
  float s3 = wsum64(xv*wattx[192+lane]);
  float p0 = wsum64(xv*watte[lane]);
  float p1 = wsum64(xv*watte[64+lane]);
  float p2 = wsum64(xv*watte[128+lane]);
  float p3 = wsum64(xv*watte[192+lane]);
  if (lane == 0){
    snpe[2*(size_t)n    ] = make_float4(s0,s1,s2,s3);
    snpe[2*(size_t)n + 1] = make_float4(p0,p1,p2,p3);
  }
}

// ---- per-edge softmax -> alphaC (col order) + alphaR (row order) ----
__global__ __launch_bounds__(256) void k_soft(const int* __restrict__ colptr,
                                              const int* __restrict__ rowC,
                                              const float* __restrict__ valC,
                                              const int* __restrict__ rposC,
                                              const float4* __restrict__ snpe,
                                              const float* __restrict__ colsum,
                                              float4* __restrict__ alphaC,
                                              float4* __restrict__ alphaR){
  int lane = threadIdx.x & 63, wid = threadIdx.x >> 6;
  int e = blockIdx.x*4 + wid;
  if (e >= N_EDGES) return;
  int s = colptr[e], cnt = colptr[e+1] - s;
  if (cnt == 0) return;
  float rcs = 1.0f / colsum[e];

  if (cnt <= 64){
    bool act = lane < cnt;
    int rp = 0; float v = 0.f;
    float4 snv = make_float4(0,0,0,0), p = make_float4(0,0,0,0);
    if (act){
      int r = rowC[s+lane];
      v = valC[s+lane];
      rp = rposC[s+lane];
      snv = snpe[2*(size_t)r];
      p   = snpe[2*(size_t)r + 1];
    }
    float se0 = wsum64(v*p.x)*rcs, se1 = wsum64(v*p.y)*rcs,
          se2 = wsum64(v*p.z)*rcs, se3 = wsum64(v*p.w)*rcs;
    float t0 = act ? lrelu2(snv.x+se0) : -1e30f;
    float t1 = act ? lrelu2(snv.y+se1) : -1e30f;
    float t2 = act ? lrelu2(snv.z+se2) : -1e30f;
    float t3 = act ? lrelu2(snv.w+se3) : -1e30f;
    float m0 = wmax64(t0), m1 = wmax64(t1), m2 = wmax64(t2), m3 = wmax64(t3);
    float e0 = act ? __expf(t0-m0) : 0.f;
    float e1 = act ? __expf(t1-m1) : 0.f;
    float e2 = act ? __expf(t2-m2) : 0.f;
    float e3 = act ? __expf(t3-m3) : 0.f;
    float q0 = wsum64(e0), q1 = wsum64(e1), q2 = wsum64(e2), q3 = wsum64(e3);
    if (act){
      float4 a = make_float4(e0/q0, e1/q1, e2/q2, e3/q3);
      alphaC[s+lane] = a;
      alphaR[rp] = a;
    }
    return;
  }
  // slow path (cnt > 64)
  float a0=0,a1=0,a2=0,a3=0;
  for (int base = 0; base < cnt; base += 64){
    int j = s + base + lane;
    if (base + lane < cnt){
      int r = rowC[j]; float v = valC[j];
      float4 p = snpe[2*(size_t)r + 1];
      a0 = fmaf(v,p.x,a0); a1 = fmaf(v,p.y,a1); a2 = fmaf(v,p.z,a2); a3 = fmaf(v,p.w,a3);
    }
  }
  float se0 = wsum64(a0)*rcs, se1 = wsum64(a1)*rcs, se2 = wsum64(a2)*rcs, se3 = wsum64(a3)*rcs;
  float m0=-1e30f,m1=-1e30f,m2=-1e30f,m3=-1e30f;
  for (int base = 0; base < cnt; base += 64){
    int j = s + base + lane;
    if (base + lane < cnt){
      float4 snv = snpe[2*(size_t)rowC[j]];
      m0 = fmaxf(m0, lrelu2(snv.x+se0)); m1 = fmaxf(m1, lrelu2(snv.y+se1));
      m2 = fmaxf(m2, lrelu2(snv.z+se2)); m3 = fmaxf(m3, lrelu2(snv.w+se3));
    }
  }
  m0 = wmax64(m0); m1 = wmax64(m1); m2 = wmax64(m2); m3 = wmax64(m3);
  float q0=0,q1=0,q2=0,q3=0;
  for (int base = 0; base < cnt; base += 64){
    int j = s + base + lane;
    if (base + lane < cnt){
      float4 snv = snpe[2*(size_t)rowC[j]];
      float e0 = __expf(lrelu2(snv.x+se0)-m0), e1 = __expf(lrelu2(snv.y+se1)-m1);
      float e2 = __expf(lrelu2(snv.z+se2)-m2), e3 = __expf(lrelu2(snv.w+se3)-m3);
      q0+=e0; q1+=e1; q2+=e2; q3+=e3;
      alphaC[j] = make_float4(e0,e1,e2,e3);
    }
  }
  q0 = wsum64(q0); q1 = wsum64(q1); q2 = wsum64(q2); q3 = wsum64(q3);
  float r0 = 1.f/q0, r1 = 1.f/q1, r2 = 1.f/q2, r3 = 1.f/q3;
  for (int base = 0; base < cnt; base += 64){
    int j = s + base + lane;
    if (base + lane < cnt){
      float4 a = alphaC[j];
      a = make_float4(a.x*r0, a.y*r1, a.z*r2, a.w*r3);
      alphaC[j] = a;
      alphaR[rposC[j]] = a;
    }
  }
}

// ---- msg1 gather in x-space: agg[e][h][d] = (1/cnt) sum_i alpha[i,h]*x[row i][d] ----
__global__ __launch_bounds__(256) void k_agg(const int* __restrict__ colptr,
                                             const int* __restrict__ rowC,
                                             const float4* __restrict__ alphaC,
                                             const float* __restrict__ x,
                                             float* __restrict__ agg){
  int lane = threadIdx.x & 63, wid = threadIdx.x >> 6;
  int e = blockIdx.x*4 + wid;
  if (e >= N_EDGES) return;
  int s = colptr[e], cnt = colptr[e+1] - s;
  float acc0=0,acc1=0,acc2=0,acc3=0;
  for (int base = 0; base < cnt; base += 64){
    int m = cnt - base; if (m > 64) m = 64;
    int r = 0; float4 al = make_float4(0,0,0,0);
    if (lane < m){ r = rowC[s+base+lane]; al = alphaC[s+base+lane]; }
#pragma unroll 4
    for (int j = 0; j < m; ++j){
      int rj = __shfl(r, j);
      float b0 = __shfl(al.x, j), b1 = __shfl(al.y, j),
            b2 = __shfl(al.z, j), b3 = __shfl(al.w, j);
      float xv = x[(size_t)rj*DIM + lane];
      acc0 = fmaf(b0, xv, acc0); acc1 = fmaf(b1, xv, acc1);
      acc2 = fmaf(b2, xv, acc2); acc3 = fmaf(b3, xv, acc3);
    }
  }
  float binv = cnt > 0 ? 1.0f/(float)cnt : 0.f;
  size_t b = (size_t)e*256;
  agg[b       + lane] = acc0*binv;
  agg[b +  64 + lane] = acc1*binv;
  agg[b + 128 + lane] = acc2*binv;
  agg[b + 192 + lane] = acc3*binv;
}

// ---- per-edge lin_w transform: eo[e][h][d] = sum_k agg[e][h][k]*lin_w[h*64+d][k] ----
// wave wid = head; lane d holds lin_w row (h*64+d) in 64 VGPRs.
__global__ __launch_bounds__(256) void k_eo(const float* __restrict__ agg,
                                            const float* __restrict__ lin_w,
                                            float* __restrict__ eo){
  int lane = threadIdx.x & 63, h = threadIdx.x >> 6;
  float w[64];
  const float4* wr = (const float4*)(lin_w + ((size_t)h*64 + lane)*64);
#pragma unroll
  for (int k = 0; k < 16; ++k){
    float4 t = wr[k];
    w[4*k] = t.x; w[4*k+1] = t.y; w[4*k+2] = t.z; w[4*k+3] = t.w;
  }
  int e0 = blockIdx.x*16, e1 = e0 + 16 < N_EDGES ? e0 + 16 : N_EDGES;
  for (int e = e0; e < e1; ++e){
    float av = agg[(size_t)e*256 + h*64 + lane];
    float o = 0.f;
#pragma unroll
    for (int k = 0; k < 64; ++k) o = fmaf(__shfl(av, k), w[k], o);
    eo[(size_t)e*256 + h*64 + lane] = o;
  }
}

// ---- msg2: per-node gather of eo rows, mean over heads -> conv ----
__global__ __launch_bounds__(256) void k_msg2(const int* __restrict__ rowptr,
                                              const int* __restrict__ colR,
                                              const float4* __restrict__ alphaR,
                                              const float* __restrict__ eo,
                                              const float* __restrict__ ddeg,
                                              float* __restrict__ conv){
  int lane = threadIdx.x & 63, wid = threadIdx.x >> 6;
  int n = blockIdx.x*4 + wid;
  if (n >= N_NODES) return;
  int s = rowptr[n], cnt = rowptr[n+1] - s;
  float a0=0,a1=0,a2=0,a3=0;
  for (int base = 0; base < cnt; base += 64){
    int m = cnt - base; if (m > 64) m = 64;
    int c = 0; float4 al = make_float4(0,0,0,0);
    if (lane < m){ c = colR[s+base+lane]; al = alphaR[s+base+lane]; }
#pragma unroll 2
    for (int j = 0; j < m; ++j){
      int cj = __shfl(c, j);
      float b0 = __shfl(al.x, j), b1 = __shfl(al.y, j),
            b2 = __shfl(al.z, j), b3 = __shfl(al.w, j);
      size_t bb = (size_t)cj*256;
      a0 = fmaf(b0, eo[bb       + lane], a0);
      a1 = fmaf(b1, eo[bb +  64 + lane], a1);
      a2 = fmaf(b2, eo[bb + 128 + lane], a2);
      a3 = fmaf(b3, eo[bb + 192 + lane], a3);
    }
  }
  float dd = ddeg[n];
  float dinv = dd > 0.f ? 0.25f/dd : 0.f;
  conv[(size_t)n*DIM + lane] = (a0+a1+a2+a3)*dinv;
}

// ---- fused epilogue ----
__global__ __launch_bounds__(256) void k_final(const float* __restrict__ x,
                                               const float* __restrict__ conv,
                                               const float* __restrict__ bias,
                                               const float* __restrict__ g1,
                                               const float* __restrict__ b1g,
                                               const float* __restrict__ g2,
                                               const float* __restrict__ b2g,
                                               const float* __restrict__ w1,
                                               const float* __restrict__ b1,
                                               const float* __restrict__ w2,
                                               const float* __restrict__ b2,
                                               float* __restrict__ out){
  __shared__ float w1s[64*65];
  __shared__ float w2s[64*65];
  for (int idx = threadIdx.x; idx < 4096; idx += 256){
    int rr = idx >> 6, cc = idx & 63;
    w1s[rr*65 + cc] = w1[idx];
    w2s[rr*65 + cc] = w2[idx];
  }
  __syncthreads();
  int wave = threadIdx.x >> 6, lane = threadIdx.x & 63;
  float biasv = bias[lane];
  float g1v = g1[lane], b1gv = b1g[lane], g2v = g2[lane], b2gv = b2g[lane];
  float b1v = b1[lane], b2v = b2[lane];
  for (int n = blockIdx.x*4 + wave; n < N_NODES; n += gridDim.x*4){
    float t = x[(size_t)n*DIM + lane] + conv[(size_t)n*DIM + lane] + biasv;
    float mu = wsum64(t) * (1.f/64.f);
    float dv = t - mu;
    float var = wsum64(dv*dv) * (1.f/64.f);
    float hv = dv * rsqrtf(var + LNEPS) * g1v + b1gv;
    float acc = b1v;
#pragma unroll
    for (int k = 0; k < 64; ++k) acc = fmaf(__shfl(hv, k), w1s[lane*65 + k], acc);
    float acc2 = b2v;
#pragma unroll
    for (int k = 0; k < 64; ++k) acc2 = fmaf(__shfl(acc, k), w2s[lane*65 + k], acc2);
    float ffn = acc2 > 0.f ? acc2 : 0.01f*acc2;
    float t2 = hv + ffn;
    float mu2 = wsum64(t2) * (1.f/64.f);
    float dv2 = t2 - mu2;
    float var2 = wsum64(dv2*dv2) * (1.f/64.f);
    out[(size_t)n*DIM + lane] = dv2 * rsqrtf(var2 + LNEPS) * g2v + b2gv;
  }
}

extern "C" void kernel_launch(void* const* d_in, const int* in_sizes, int n_in,
                              void* d_out, int out_size, void* d_ws, size_t ws_size,
                              hipStream_t stream){
  const float* x     = (const float*)d_in[0];
  const int*   row   = (const int*)d_in[1];
  const int*   col   = (const int*)d_in[2];
  const float* val   = (const float*)d_in[3];
  const float* lin_w = (const float*)d_in[5];
  const float* att   = (const float*)d_in[6];
  const float* bias  = (const float*)d_in[7];
  const float* g1    = (const float*)d_in[8];
  const float* b1g   = (const float*)d_in[9];
  const float* g2    = (const float*)d_in[10];
  const float* b2g   = (const float*)d_in[11];
  const float* w1    = (const float*)d_in[12];
  const float* b1    = (const float*)d_in[13];
  const float* w2    = (const float*)d_in[14];
  const float* b2    = (const float*)d_in[15];
  float* out = (float*)d_out;
  float* ws  = (float*)d_ws;

  constexpr size_t E = N_EDGES, Nn = N_NODES;
  // zeroed region first -> one memset
  constexpr size_t o_ecnt   = 0;                   // E ints
  constexpr size_t o_ncnt   = o_ecnt + E;          // N ints
  constexpr size_t o_ecur   = o_ncnt + Nn;         // E ints
  constexpr size_t o_ncur   = o_ecur + E;          // N ints
  constexpr size_t o_colsum = o_ncur + Nn;         // E f
  constexpr size_t o_ddeg   = o_colsum + E;        // N f
  constexpr size_t ZEND     = o_ddeg + Nn;
  constexpr size_t o_colptr = ZEND;                // E+4 ints
  constexpr size_t o_rowptr = o_colptr + E + 4;    // N+4 ints
  constexpr size_t o_bsumE  = o_rowptr + Nn + 4;   // 256 ints
  constexpr size_t o_bsumN  = o_bsumE + 256;       // 256 ints
  constexpr size_t o_rowC   = o_bsumN + 256;       // NNZ ints
  constexpr size_t o_valC   = o_rowC + NNZ_;       // NNZ f
  constexpr size_t o_rposC  = o_valC + NNZ_;       // NNZ ints
  constexpr size_t o_colR   = o_rposC + NNZ_;      // NNZ ints
  constexpr size_t o_wattx  = o_colR + NNZ_;       // 256 f
  constexpr size_t o_watte  = o_wattx + 256;       // 256 f
  constexpr size_t o_snpe   = o_watte + 256;       // 8N f (float4 pairs)
  constexpr size_t o_alphaC = o_snpe + 8*Nn;       // 4*NNZ f
  constexpr size_t o_alphaR = o_alphaC + 4*(size_t)NNZ_; // 4*NNZ f
  constexpr size_t o_agg    = o_alphaR + 4*(size_t)NNZ_; // 256*E f
  constexpr size_t o_eo     = o_agg + 256*E;       // 256*E f
  constexpr size_t o_conv   = o_eo + 256*E;        // 64*N f

  int*    ecnt   = (int*)(ws + o_ecnt);
  int*    ncnt   = (int*)(ws + o_ncnt);
  int*    ecur   = (int*)(ws + o_ecur);
  int*    ncur   = (int*)(ws + o_ncur);
  float*  colsum = ws + o_colsum;
  float*  ddeg   = ws + o_ddeg;
  int*    colptr = (int*)(ws + o_colptr);
  int*    rowptr = (int*)(ws + o_rowptr);
  int*    bsumE  = (int*)(ws + o_bsumE);
  int*    bsumN  = (int*)(ws + o_bsumN);
  int*    rowC   = (int*)(ws + o_rowC);
  float*  valC   = ws + o_valC;
  int*    rposC  = (int*)(ws + o_rposC);
  int*    colR   = (int*)(ws + o_colR);
  float*  wattx  = ws + o_wattx;
  float*  watte  = ws + o_watte;
  float4* snpe   = (float4*)(ws + o_snpe);
  float4* alphaC = (float4*)(ws + o_alphaC);
  float4* alphaR = (float4*)(ws + o_alphaR);
  float*  agg    = ws + o_agg;
  float*  eo     = ws + o_eo;
  float*  conv   = ws + o_conv;

  hipMemsetAsync(ws, 0, ZEND*sizeof(float), stream);

  k_hist<<<(NNZ_+255)/256, 256, 0, stream>>>(row, col, val, ecnt, ncnt, colsum, ddeg);

  int nbE = (int)((E + 1023)/1024);    // 20
  int nbN = (int)((Nn + 1023)/1024);   // 98
  k_scanA<<<nbE, 1024, 0, stream>>>(ecnt, colptr, bsumE, (int)E);
  k_scanB<<<1, 256, 0, stream>>>(bsumE, nbE, colptr, (int)E);
  k_scanC<<<nbE, 1024, 0, stream>>>(colptr, bsumE, (int)E);
  k_scanA<<<nbN, 1024, 0, stream>>>(ncnt, rowptr, bsumN, (int)Nn);
  k_scanB<<<1, 256, 0, stream>>>(bsumN, nbN, rowptr, (int)Nn);
  k_scanC<<<nbN, 1024, 0, stream>>>(rowptr, bsumN, (int)Nn);

  k_scatter<<<(NNZ_+255)/256, 256, 0, stream>>>(row, col, val, colptr, rowptr,
                                                ecur, ncur, rowC, valC, rposC, colR);

  k_watt<<<1, 256, 0, stream>>>(lin_w, att, wattx, watte);
  k_pre<<<(int)((Nn+3)/4), 256, 0, stream>>>(x, wattx, watte, snpe);
  k_soft<<<(int)((E+3)/4), 256, 0, stream>>>(colptr, rowC, valC, rposC, snpe, colsum, alphaC, alphaR);
  k_agg<<<(int)((E+3)/4), 256, 0, stream>>>(colptr, rowC, alphaC, x, agg);
  k_eo<<<(int)((E+15)/16), 256, 0, stream>>>(agg, lin_w, eo);
  k_msg2<<<(int)((Nn+3)/4), 256, 0, stream>>>(rowptr, colR, alphaR, eo, ddeg, conv);
  k_final<<<1024, 256, 0, stream>>>(x, conv, bias, g1, b1g, g2, b2g, w1, b1, w2, b2, out);
}

// Round 4
// 532.843 us; speedup vs baseline: 2.0859x; 1.1555x over previous
//
#include <hip/hip_runtime.h>

#define N_NODES 100000
#define N_EDGES 20000
#define DIM 64
#define HEADS 4
#define NNZ_ 500000
#define LNEPS 1e-5f

__device__ __forceinline__ float wsum64(float v){
#pragma unroll
  for (int off = 32; off; off >>= 1) v += __shfl_xor(v, off);
  return v;
}
__device__ __forceinline__ float wmax64(float v){
#pragma unroll
  for (int off = 32; off; off >>= 1) v = fmaxf(v, __shfl_xor(v, off));
  return v;
}
__device__ __forceinline__ float lrelu2(float a){ return a > 0.f ? a : 0.2f*a; }

// ---- histogram + degree sums ----
__global__ __launch_bounds__(256) void k_hist(const int* __restrict__ row,
                                              const int* __restrict__ col,
                                              const float* __restrict__ val,
                                              int* __restrict__ ecnt, int* __restrict__ ncnt,
                                              float* __restrict__ colsum, float* __restrict__ ddeg){
  int i = blockIdx.x*256 + threadIdx.x;
  if (i >= NNZ_) return;
  int c = col[i], r = row[i];
  atomicAdd(&ecnt[c], 1);
  atomicAdd(&ncnt[r], 1);
  atomicAdd(&colsum[c], val[i]);
  atomicAdd(&ddeg[r], val[c]);   // reference: adj_val[adj_col[i]]
}

// ---- hierarchical scan ----
__global__ __launch_bounds__(1024) void k_scanA(const int* __restrict__ cnt,
                                                int* __restrict__ ptr,
                                                int* __restrict__ bsum, int n){
  __shared__ int wsums[16];
  int idx = blockIdx.x*1024 + threadIdx.x;
  int lane = threadIdx.x & 63, wid = threadIdx.x >> 6;
  int v = (idx < n) ? cnt[idx] : 0;
  int s = v;
#pragma unroll
  for (int off = 1; off < 64; off <<= 1){
    int t = __shfl_up(s, off);
    if (lane >= off) s += t;
  }
  if (lane == 63) wsums[wid] = s;
  __syncthreads();
  if (wid == 0 && lane < 16){
    int ws = wsums[lane];
    int t = ws;
#pragma unroll
    for (int off = 1; off < 16; off <<= 1){
      int u = __shfl_up(t, off);
      if (lane >= off) t += u;
    }
    wsums[lane] = t - ws;
  }
  __syncthreads();
  if (idx < n) ptr[idx] = wsums[wid] + s - v;
  if (threadIdx.x == 1023) bsum[blockIdx.x] = wsums[15] + s;
}

__global__ __launch_bounds__(256) void k_scanB(int* __restrict__ bsum, int nb,
                                               int* __restrict__ ptr, int n){
  __shared__ int sh[256];
  int t = threadIdx.x;
  int v = (t < nb) ? bsum[t] : 0;
  sh[t] = v;
  __syncthreads();
  for (int off = 1; off < 256; off <<= 1){
    int u = (t >= off) ? sh[t-off] : 0;
    __syncthreads();
    sh[t] += u;
    __syncthreads();
  }
  if (t < nb) bsum[t] = sh[t] - v;
  if (t == nb-1) ptr[n] = sh[t];
}

__global__ __launch_bounds__(1024) void k_scanC(int* __restrict__ ptr,
                                                const int* __restrict__ bsum, int n){
  int idx = blockIdx.x*1024 + threadIdx.x;
  if (idx < n) ptr[idx] += bsum[blockIdx.x];
}

// ---- scatter: permuted metadata copies ----
__global__ __launch_bounds__(256) void k_scatter(const int* __restrict__ row,
                                                 const int* __restrict__ col,
                                                 const float* __restrict__ val,
                                                 const int* __restrict__ colptr,
                                                 const int* __restrict__ rowptr,
                                                 int* __restrict__ ecur, int* __restrict__ ncur,
                                                 int* __restrict__ rowC, float* __restrict__ valC,
                                                 int* __restrict__ rposC, int* __restrict__ colR){
  int i = blockIdx.x*256 + threadIdx.x;
  if (i >= NNZ_) return;
  int c = col[i], r = row[i];
  int p = atomicAdd(&ecur[c], 1);
  int q = atomicAdd(&ncur[r], 1);
  int cpos = colptr[c] + p;
  int rpos = rowptr[r] + q;
  rowC[cpos] = r;
  valC[cpos] = val[i];
  rposC[cpos] = rpos;
  colR[rpos] = c;
}

// ---- folded attention vectors ----
__global__ __launch_bounds__(256) void k_watt(const float* __restrict__ lin_w,
                                              const float* __restrict__ att,
                                              float* __restrict__ wattx,
                                              float* __restrict__ watte){
  int j = threadIdx.x;           // j = h*64 + k
  int h = j >> 6;
  float sx = 0.f, se = 0.f;
#pragma unroll
  for (int d = 0; d < DIM; ++d){
    float w = lin_w[(h*DIM + d)*DIM + (j & 63)];
    sx = fmaf(att[h*2*DIM + d],       w, sx);
    se = fmaf(att[h*2*DIM + DIM + d], w, se);
  }
  wattx[j] = sx;
  watte[j] = se;
}

// ---- folded FFN: Wf = w2@w1, bp = w2@b1 + b2  (no activation between w1,w2) ----
__global__ __launch_bounds__(256) void k_wfold(const float* __restrict__ w1,
                                               const float* __restrict__ w2,
                                               const float* __restrict__ b1,
                                               const float* __restrict__ b2,
                                               float* __restrict__ Wf,
                                               float* __restrict__ bp){
  int tid = threadIdx.x;
#pragma unroll
  for (int m = 0; m < 16; ++m){
    int idx = m*256 + tid;
    int o = idx >> 6, k = idx & 63;
    float s = 0.f;
#pragma unroll
    for (int i = 0; i < 64; ++i)
      s = fmaf(w2[o*64 + i], w1[i*64 + k], s);
    Wf[idx] = s;
  }
  if (tid < 64){
    float s = b2[tid];
#pragma unroll
    for (int i = 0; i < 64; ++i)
      s = fmaf(w2[tid*64 + i], b1[i], s);
    bp[tid] = s;
  }
}

// ---- per-node projections, packed ----
__global__ __launch_bounds__(256) void k_pre(const float* __restrict__ x,
                                             const float* __restrict__ wattx,
                                             const float* __restrict__ watte,
                                             float4* __restrict__ snpe){
  int lane = threadIdx.x & 63, wid = threadIdx.x >> 6;
  int n = blockIdx.x*4 + wid;
  if (n >= N_NODES) return;
  float xv = x[(size_t)n*DIM + lane];
  float s0 = wsum64(xv*wattx[lane]);
  float s1 = wsum64(xv*wattx[64+lane]);
  float s2 = wsum64(xv*wattx[128+lane]);
  float s3 = wsum64(xv*wattx[192+lane]);
  float p0 = wsum64(xv*watte[lane]);
  float p1 = wsum64(xv*watte[64+lane]);
  float p2 = wsum64(xv*watte[128+lane]);
  float p3 = wsum64(xv*watte[192+lane]);
  if (lane == 0){
    snpe[2*(size_t)n    ] = make_float4(s0,s1,s2,s3);
    snpe[2*(size_t)n + 1] = make_float4(p0,p1,p2,p3);
  }
}

// ---- per-edge softmax -> alphaC + alphaR ----
__global__ __launch_bounds__(256) void k_soft(const int* __restrict__ colptr,
                                              const int* __restrict__ rowC,
                                              const float* __restrict__ valC,
                                              const int* __restrict__ rposC,
                                              const float4* __restrict__ snpe,
                                              const float* __restrict__ colsum,
                                              float4* __restrict__ alphaC,
                                              float4* __restrict__ alphaR){
  int lane = threadIdx.x & 63, wid = threadIdx.x >> 6;
  int e = blockIdx.x*4 + wid;
  if (e >= N_EDGES) return;
  int s = colptr[e], cnt = colptr[e+1] - s;
  if (cnt == 0) return;
  float rcs = 1.0f / colsum[e];

  if (cnt <= 64){
    bool act = lane < cnt;
    int rp = 0; float v = 0.f;
    float4 snv = make_float4(0,0,0,0), p = make_float4(0,0,0,0);
    if (act){
      int r = rowC[s+lane];
      v = valC[s+lane];
      rp = rposC[s+lane];
      snv = snpe[2*(size_t)r];
      p   = snpe[2*(size_t)r + 1];
    }
    float se0 = wsum64(v*p.x)*rcs, se1 = wsum64(v*p.y)*rcs,
          se2 = wsum64(v*p.z)*rcs, se3 = wsum64(v*p.w)*rcs;
    float t0 = act ? lrelu2(snv.x+se0) : -1e30f;
    float t1 = act ? lrelu2(snv.y+se1) : -1e30f;
    float t2 = act ? lrelu2(snv.z+se2) : -1e30f;
    float t3 = act ? lrelu2(snv.w+se3) : -1e30f;
    float m0 = wmax64(t0), m1 = wmax64(t1), m2 = wmax64(t2), m3 = wmax64(t3);
    float e0 = act ? __expf(t0-m0) : 0.f;
    float e1 = act ? __expf(t1-m1) : 0.f;
    float e2 = act ? __expf(t2-m2) : 0.f;
    float e3 = act ? __expf(t3-m3) : 0.f;
    float q0 = wsum64(e0), q1 = wsum64(e1), q2 = wsum64(e2), q3 = wsum64(e3);
    if (act){
      float4 a = make_float4(e0/q0, e1/q1, e2/q2, e3/q3);
      alphaC[s+lane] = a;
      alphaR[rp] = a;
    }
    return;
  }
  // slow path (cnt > 64)
  float a0=0,a1=0,a2=0,a3=0;
  for (int base = 0; base < cnt; base += 64){
    int j = s + base + lane;
    if (base + lane < cnt){
      int r = rowC[j]; float v = valC[j];
      float4 p = snpe[2*(size_t)r + 1];
      a0 = fmaf(v,p.x,a0); a1 = fmaf(v,p.y,a1); a2 = fmaf(v,p.z,a2); a3 = fmaf(v,p.w,a3);
    }
  }
  float se0 = wsum64(a0)*rcs, se1 = wsum64(a1)*rcs, se2 = wsum64(a2)*rcs, se3 = wsum64(a3)*rcs;
  float m0=-1e30f,m1=-1e30f,m2=-1e30f,m3=-1e30f;
  for (int base = 0; base < cnt; base += 64){
    int j = s + base + lane;
    if (base + lane < cnt){
      float4 snv = snpe[2*(size_t)rowC[j]];
      m0 = fmaxf(m0, lrelu2(snv.x+se0)); m1 = fmaxf(m1, lrelu2(snv.y+se1));
      m2 = fmaxf(m2, lrelu2(snv.z+se2)); m3 = fmaxf(m3, lrelu2(snv.w+se3));
    }
  }
  m0 = wmax64(m0); m1 = wmax64(m1); m2 = wmax64(m2); m3 = wmax64(m3);
  float q0=0,q1=0,q2=0,q3=0;
  for (int base = 0; base < cnt; base += 64){
    int j = s + base + lane;
    if (base + lane < cnt){
      float4 snv = snpe[2*(size_t)rowC[j]];
      float e0 = __expf(lrelu2(snv.x+se0)-m0), e1 = __expf(lrelu2(snv.y+se1)-m1);
      float e2 = __expf(lrelu2(snv.z+se2)-m2), e3 = __expf(lrelu2(snv.w+se3)-m3);
      q0+=e0; q1+=e1; q2+=e2; q3+=e3;
      alphaC[j] = make_float4(e0,e1,e2,e3);
    }
  }
  q0 = wsum64(q0); q1 = wsum64(q1); q2 = wsum64(q2); q3 = wsum64(q3);
  float r0 = 1.f/q0, r1 = 1.f/q1, r2 = 1.f/q2, r3 = 1.f/q3;
  for (int base = 0; base < cnt; base += 64){
    int j = s + base + lane;
    if (base + lane < cnt){
      float4 a = alphaC[j];
      a = make_float4(a.x*r0, a.y*r1, a.z*r2, a.w*r3);
      alphaC[j] = a;
      alphaR[rposC[j]] = a;
    }
  }
}

// ---- msg1 gather in x-space ----
__global__ __launch_bounds__(256) void k_agg(const int* __restrict__ colptr,
                                             const int* __restrict__ rowC,
                                             const float4* __restrict__ alphaC,
                                             const float* __restrict__ x,
                                             float* __restrict__ agg){
  int lane = threadIdx.x & 63, wid = threadIdx.x >> 6;
  int e = blockIdx.x*4 + wid;
  if (e >= N_EDGES) return;
  int s = colptr[e], cnt = colptr[e+1] - s;
  float acc0=0,acc1=0,acc2=0,acc3=0;
  for (int base = 0; base < cnt; base += 64){
    int m = cnt - base; if (m > 64) m = 64;
    int r = 0; float4 al = make_float4(0,0,0,0);
    if (lane < m){ r = rowC[s+base+lane]; al = alphaC[s+base+lane]; }
#pragma unroll 4
    for (int j = 0; j < m; ++j){
      int rj = __shfl(r, j);
      float b0 = __shfl(al.x, j), b1 = __shfl(al.y, j),
            b2 = __shfl(al.z, j), b3 = __shfl(al.w, j);
      float xv = x[(size_t)rj*DIM + lane];
      acc0 = fmaf(b0, xv, acc0); acc1 = fmaf(b1, xv, acc1);
      acc2 = fmaf(b2, xv, acc2); acc3 = fmaf(b3, xv, acc3);
    }
  }
  float binv = cnt > 0 ? 1.0f/(float)cnt : 0.f;
  size_t b = (size_t)e*256;
  agg[b       + lane] = acc0*binv;
  agg[b +  64 + lane] = acc1*binv;
  agg[b + 128 + lane] = acc2*binv;
  agg[b + 192 + lane] = acc3*binv;
}

// ---- per-edge lin_w transform ----
__global__ __launch_bounds__(256) void k_eo(const float* __restrict__ agg,
                                            const float* __restrict__ lin_w,
                                            float* __restrict__ eo){
  int lane = threadIdx.x & 63, h = threadIdx.x >> 6;
  float w[64];
  const float4* wr = (const float4*)(lin_w + ((size_t)h*64 + lane)*64);
#pragma unroll
  for (int k = 0; k < 16; ++k){
    float4 t = wr[k];
    w[4*k] = t.x; w[4*k+1] = t.y; w[4*k+2] = t.z; w[4*k+3] = t.w;
  }
  int e0 = blockIdx.x*16, e1 = e0 + 16 < N_EDGES ? e0 + 16 : N_EDGES;
  for (int e = e0; e < e1; ++e){
    float av = agg[(size_t)e*256 + h*64 + lane];
    float o = 0.f;
#pragma unroll
    for (int k = 0; k < 64; ++k) o = fmaf(__shfl(av, k), w[k], o);
    eo[(size_t)e*256 + h*64 + lane] = o;
  }
}

// ---- fused: msg2 gather + LN1 + folded FFN + LN2, 4 nodes per wave ----
__global__ __launch_bounds__(256) void k_final2(const float* __restrict__ x,
                                                const int* __restrict__ rowptr,
                                                const int* __restrict__ colR,
                                                const float4* __restrict__ alphaR,
                                                const float* __restrict__ eo,
                                                const float* __restrict__ ddeg,
                                                const float* __restrict__ bias,
                                                const float* __restrict__ g1,
                                                const float* __restrict__ b1g,
                                                const float* __restrict__ g2,
                                                const float* __restrict__ b2g,
                                                const float* __restrict__ Wf,
                                                const float* __restrict__ bp,
                                                float* __restrict__ out){
  int lane = threadIdx.x & 63, wid = threadIdx.x >> 6;
  // folded FFN weight row for this lane (64 VGPRs)
  float w[64];
  const float4* wr = (const float4*)(Wf + (size_t)lane*64);
#pragma unroll
  for (int k = 0; k < 16; ++k){
    float4 t = wr[k];
    w[4*k] = t.x; w[4*k+1] = t.y; w[4*k+2] = t.z; w[4*k+3] = t.w;
  }
  float biasv = bias[lane], bpv = bp[lane];
  float g1v = g1[lane], b1gv = b1g[lane], g2v = g2[lane], b2gv = b2g[lane];

  int nbase = blockIdx.x*16 + wid*4;
  float hs[4];

  // phase 1: per node, gather conv (msg2) then LN1 -> h
#pragma unroll
  for (int j = 0; j < 4; ++j){
    int n = nbase + j;
    int s = rowptr[n], cnt = rowptr[n+1] - s;
    float a0=0,a1=0,a2=0,a3=0;
    for (int base = 0; base < cnt; base += 64){
      int m = cnt - base; if (m > 64) m = 64;
      int c = 0; float4 al = make_float4(0,0,0,0);
      if (lane < m){ c = colR[s+base+lane]; al = alphaR[s+base+lane]; }
#pragma unroll 2
      for (int i = 0; i < m; ++i){
        int ci = __shfl(c, i);
        float q0 = __shfl(al.x, i), q1 = __shfl(al.y, i),
              q2 = __shfl(al.z, i), q3 = __shfl(al.w, i);
        size_t bb = (size_t)ci*256;
        a0 = fmaf(q0, eo[bb       + lane], a0);
        a1 = fmaf(q1, eo[bb +  64 + lane], a1);
        a2 = fmaf(q2, eo[bb + 128 + lane], a2);
        a3 = fmaf(q3, eo[bb + 192 + lane], a3);
      }
    }
    float dd = ddeg[n];
    float dinv = dd > 0.f ? 0.25f/dd : 0.f;
    float conv = (a0+a1+a2+a3)*dinv;
    float t = x[(size_t)n*DIM + lane] + conv + biasv;
    float mu = wsum64(t) * (1.f/64.f);
    float dv = t - mu;
    float var = wsum64(dv*dv) * (1.f/64.f);
    hs[j] = dv * rsqrtf(var + LNEPS) * g1v + b1gv;
  }

  // phase 2: folded FFN, 4 independent chains
  float a0 = bpv, a1 = bpv, a2 = bpv, a3 = bpv;
#pragma unroll
  for (int k = 0; k < 64; ++k){
    a0 = fmaf(__shfl(hs[0], k), w[k], a0);
    a1 = fmaf(__shfl(hs[1], k), w[k], a1);
    a2 = fmaf(__shfl(hs[2], k), w[k], a2);
    a3 = fmaf(__shfl(hs[3], k), w[k], a3);
  }

  // phase 3: leaky + residual + LN2 + store
  float fa[4] = {a0, a1, a2, a3};
#pragma unroll
  for (int j = 0; j < 4; ++j){
    int n = nbase + j;
    float ffn = fa[j] > 0.f ? fa[j] : 0.01f*fa[j];
    float t2 = hs[j] + ffn;
    float mu2 = wsum64(t2) * (1.f/64.f);
    float dv2 = t2 - mu2;
    float var2 = wsum64(dv2*dv2) * (1.f/64.f);
    out[(size_t)n*DIM + lane] = dv2 * rsqrtf(var2 + LNEPS) * g2v + b2gv;
  }
}

extern "C" void kernel_launch(void* const* d_in, const int* in_sizes, int n_in,
                              void* d_out, int out_size, void* d_ws, size_t ws_size,
                              hipStream_t stream){
  const float* x     = (const float*)d_in[0];
  const int*   row   = (const int*)d_in[1];
  const int*   col   = (const int*)d_in[2];
  const float* val   = (const float*)d_in[3];
  const float* lin_w = (const float*)d_in[5];
  const float* att   = (const float*)d_in[6];
  const float* bias  = (const float*)d_in[7];
  const float* g1    = (const float*)d_in[8];
  const float* b1g   = (const float*)d_in[9];
  const float* g2    = (const float*)d_in[10];
  const float* b2g   = (const float*)d_in[11];
  const float* w1    = (const float*)d_in[12];
  const float* b1    = (const float*)d_in[13];
  const float* w2    = (const float*)d_in[14];
  const float* b2    = (const float*)d_in[15];
  float* out = (float*)d_out;
  float* ws  = (float*)d_ws;

  constexpr size_t E = N_EDGES, Nn = N_NODES;
  constexpr size_t o_ecnt   = 0;                   // E ints (zeroed)
  constexpr size_t o_ncnt   = o_ecnt + E;          // N ints
  constexpr size_t o_ecur   = o_ncnt + Nn;         // E ints
  constexpr size_t o_ncur   = o_ecur + E;          // N ints
  constexpr size_t o_colsum = o_ncur + Nn;         // E f
  constexpr size_t o_ddeg   = o_colsum + E;        // N f
  constexpr size_t ZEND     = o_ddeg + Nn;
  constexpr size_t o_colptr = ZEND;                // E+4 ints
  constexpr size_t o_rowptr = o_colptr + E + 4;    // N+4 ints
  constexpr size_t o_bsumE  = o_rowptr + Nn + 4;   // 256 ints
  constexpr size_t o_bsumN  = o_bsumE + 256;       // 256 ints
  constexpr size_t o_rowC   = o_bsumN + 256;       // NNZ ints
  constexpr size_t o_valC   = o_rowC + NNZ_;       // NNZ f
  constexpr size_t o_rposC  = o_valC + NNZ_;       // NNZ ints
  constexpr size_t o_colR   = o_rposC + NNZ_;      // NNZ ints
  constexpr size_t o_wattx  = o_colR + NNZ_;       // 256 f
  constexpr size_t o_watte  = o_wattx + 256;       // 256 f
  constexpr size_t o_Wf     = o_watte + 256;       // 4096 f
  constexpr size_t o_bp     = o_Wf + 4096;         // 64 f
  constexpr size_t o_snpe   = o_bp + 64;           // 8N f
  constexpr size_t o_alphaC = o_snpe + 8*Nn;       // 4*NNZ f
  constexpr size_t o_alphaR = o_alphaC + 4*(size_t)NNZ_; // 4*NNZ f
  constexpr size_t o_agg    = o_alphaR + 4*(size_t)NNZ_; // 256*E f
  constexpr size_t o_eo     = o_agg + 256*E;       // 256*E f

  int*    ecnt   = (int*)(ws + o_ecnt);
  int*    ncnt   = (int*)(ws + o_ncnt);
  int*    ecur   = (int*)(ws + o_ecur);
  int*    ncur   = (int*)(ws + o_ncur);
  float*  colsum = ws + o_colsum;
  float*  ddeg   = ws + o_ddeg;
  int*    colptr = (int*)(ws + o_colptr);
  int*    rowptr = (int*)(ws + o_rowptr);
  int*    bsumE  = (int*)(ws + o_bsumE);
  int*    bsumN  = (int*)(ws + o_bsumN);
  int*    rowC   = (int*)(ws + o_rowC);
  float*  valC   = ws + o_valC;
  int*    rposC  = (int*)(ws + o_rposC);
  int*    colR   = (int*)(ws + o_colR);
  float*  wattx  = ws + o_wattx;
  float*  watte  = ws + o_watte;
  float*  Wf     = ws + o_Wf;
  float*  bp     = ws + o_bp;
  float4* snpe   = (float4*)(ws + o_snpe);
  float4* alphaC = (float4*)(ws + o_alphaC);
  float4* alphaR = (float4*)(ws + o_alphaR);
  float*  agg    = ws + o_agg;
  float*  eo     = ws + o_eo;

  hipMemsetAsync(ws, 0, ZEND*sizeof(float), stream);

  k_hist<<<(NNZ_+255)/256, 256, 0, stream>>>(row, col, val, ecnt, ncnt, colsum, ddeg);

  int nbE = (int)((E + 1023)/1024);
  int nbN = (int)((Nn + 1023)/1024);
  k_scanA<<<nbE, 1024, 0, stream>>>(ecnt, colptr, bsumE, (int)E);
  k_scanB<<<1, 256, 0, stream>>>(bsumE, nbE, colptr, (int)E);
  k_scanC<<<nbE, 1024, 0, stream>>>(colptr, bsumE, (int)E);
  k_scanA<<<nbN, 1024, 0, stream>>>(ncnt, rowptr, bsumN, (int)Nn);
  k_scanB<<<1, 256, 0, stream>>>(bsumN, nbN, rowptr, (int)Nn);
  k_scanC<<<nbN, 1024, 0, stream>>>(rowptr, bsumN, (int)Nn);

  k_scatter<<<(NNZ_+255)/256, 256, 0, stream>>>(row, col, val, colptr, rowptr,
                                                ecur, ncur, rowC, valC, rposC, colR);

  k_watt<<<1, 256, 0, stream>>>(lin_w, att, wattx, watte);
  k_wfold<<<1, 256, 0, stream>>>(w1, w2, b1, b2, Wf, bp);
  k_pre<<<(int)((Nn+3)/4), 256, 0, stream>>>(x, wattx, watte, snpe);
  k_soft<<<(int)((E+3)/4), 256, 0, stream>>>(colptr, rowC, valC, rposC, snpe, colsum, alphaC, alphaR);
  k_agg<<<(int)((E+3)/4), 256, 0, stream>>>(colptr, rowC, alphaC, x, agg);
  k_eo<<<(int)((E+15)/16), 256, 0, stream>>>(agg, lin_w, eo);
  k_final2<<<(int)(Nn/16), 256, 0, stream>>>(x, rowptr, colR, alphaR, eo, ddeg,
                                             bias, g1, b1g, g2, b2g, Wf, bp, out);
}